// Round 1
// baseline (1049.519 us; speedup 1.0000x reference)
//
#include <hip/hip_runtime.h>
#include <math.h>

#define B    32
#define INF  784
#define H1   1024
#define H2   1024
#define NC   10
#define EPSV 0.1f

// ---------------------------------------------------------------------------
// K1: layer-1.  One block per i (row of W1).  Computes nom1[b,i], r1[i],
// then d1,l1 per (b,i).  Stores b-major: d1B/t1B/dnB [b][H1]
//   t1 = d1*l1m,  dn = d1*nom1
// ---------------------------------------------------------------------------
__global__ __launch_bounds__(256) void k1_layer1(
    const float* __restrict__ x, const float* __restrict__ W1,
    const float* __restrict__ b1,
    float* __restrict__ d1B, float* __restrict__ t1B, float* __restrict__ dnB)
{
  int i = blockIdx.x;
  int t = threadIdx.x;
  const float* w = W1 + (size_t)i * INF;
  float acc[B];
#pragma unroll
  for (int b = 0; b < B; b++) acc[b] = 0.f;
  float wabs = 0.f;
  for (int k = t; k < INF; k += 256) {
    float wv = w[k];
    wabs += fabsf(wv);
#pragma unroll
    for (int b = 0; b < B; b++) acc[b] = fmaf(x[b * INF + k], wv, acc[b]);
  }
#pragma unroll
  for (int off = 32; off > 0; off >>= 1) {
#pragma unroll
    for (int b = 0; b < B; b++) acc[b] += __shfl_down(acc[b], off, 64);
    wabs += __shfl_down(wabs, off, 64);
  }
  __shared__ float red[4][B + 1];
  int wave = t >> 6, lane = t & 63;
  if (lane == 0) {
#pragma unroll
    for (int b = 0; b < B; b++) red[wave][b] = acc[b];
    red[wave][B] = wabs;
  }
  __syncthreads();
  if (t < B) {
    float s = red[0][t] + red[1][t] + red[2][t] + red[3][t];
    float r = EPSV * (red[0][B] + red[1][B] + red[2][B] + red[3][B]);
    float nom = s + b1[i];
    float zl = nom - r, zu = nom + r;
    float d, l;
    if (zl >= 0.f)      { d = 1.f;            l = 0.f; }
    else if (zu > 0.f)  { d = zu / (zu - zl); l = zl;  }
    else                { d = 0.f;            l = 0.f; }
    d1B[(size_t)t * H1 + i] = d;
    t1B[(size_t)t * H1 + i] = d * l;
    dnB[(size_t)t * H1 + i] = d * nom;
  }
}

// ---------------------------------------------------------------------------
// K2: A / crossl / crossu matvecs.  One block per j (row of W2).
//   A[j,b]  = b2[j] + sum_i W2[j,i]*dn[b,i]
//   Cl[j,b] = sum_i relu(-W2[j,i])*t1[b,i]
//   Cu[j,b] = sum_i relu( W2[j,i])*t1[b,i]
// Each wave owns 8 consecutive b.  Layout of outputs: [j*B + b].
// ---------------------------------------------------------------------------
__global__ __launch_bounds__(256) void k2_matvec(
    const float* __restrict__ W2, const float* __restrict__ b2,
    const float* __restrict__ dnB, const float* __restrict__ t1B,
    float* __restrict__ A, float* __restrict__ Cl, float* __restrict__ Cu)
{
  int j = blockIdx.x;
  int t = threadIdx.x;
  int wave = t >> 6, lane = t & 63;
  int b0 = wave * 8;
  float aA[8] = {}, aCl[8] = {}, aCu[8] = {};
  const float* __restrict__ w2 = W2 + (size_t)j * H1;
  for (int i = lane; i < H1; i += 64) {
    float wv = w2[i];
    float wp = fmaxf(wv, 0.f), wn = fmaxf(-wv, 0.f);
#pragma unroll
    for (int r = 0; r < 8; r++) {
      float dv = dnB[(size_t)(b0 + r) * H1 + i];
      float tv = t1B[(size_t)(b0 + r) * H1 + i];
      aA[r]  = fmaf(wv, dv, aA[r]);
      aCl[r] = fmaf(wn, tv, aCl[r]);
      aCu[r] = fmaf(wp, tv, aCu[r]);
    }
  }
#pragma unroll
  for (int off = 32; off > 0; off >>= 1) {
#pragma unroll
    for (int r = 0; r < 8; r++) {
      aA[r]  += __shfl_down(aA[r],  off, 64);
      aCl[r] += __shfl_down(aCl[r], off, 64);
      aCu[r] += __shfl_down(aCu[r], off, 64);
    }
  }
  if (lane == 0) {
    float bj = b2[j];
#pragma unroll
    for (int r = 0; r < 8; r++) {
      A [(size_t)j * B + b0 + r] = aA[r] + bj;
      Cl[(size_t)j * B + b0 + r] = aCl[r];
      Cu[(size_t)j * B + b0 + r] = aCu[r];
    }
  }
}

// ---------------------------------------------------------------------------
// K3: the big one.  E[j,b] += eps * sum_{k tile} | sum_i W2[j,i]*d1[b,i]*W1[i,k] |
// Tiled fp32 GEMM: per block: b fixed, 64(j) x 64(k) tile, K-loop over i in 16s.
// grid = (ceil(784/64)=13, 1024/64=16, 32)
// ---------------------------------------------------------------------------
#define TJ 64
#define TK 64
#define TI 16
__global__ __launch_bounds__(256) void k3_egemm(
    const float* __restrict__ W2, const float* __restrict__ W1,
    const float* __restrict__ d1B, float* __restrict__ E)
{
  int b  = blockIdx.z;
  int j0 = blockIdx.y * TJ;
  int k0 = blockIdx.x * TK;
  int t  = threadIdx.x;
  int tx = t & 15;   // k quad
  int ty = t >> 4;   // j quad

  __shared__ float Ds[H1];          // d1 for this b
  __shared__ float As[TI][TJ + 4];  // A2[i][j] = W2[j,i]*d1[b,i]
  __shared__ float Ws[TI][TK];      // W1[i][k]
  __shared__ float redE[TJ][17];

  for (int idx = t; idx < H1; idx += 256) Ds[idx] = d1B[(size_t)b * H1 + idx];
  __syncthreads();

  float acc[4][4] = {};
  for (int i0 = 0; i0 < H1; i0 += TI) {
    // stage As: thread -> (j row = t>>2, i quad = (t&3)*4), float4 along i
    {
      int jr = t >> 2;
      int ib = (t & 3) * 4;
      float4 w4 = *reinterpret_cast<const float4*>(&W2[(size_t)(j0 + jr) * H1 + i0 + ib]);
      As[ib + 0][jr] = w4.x * Ds[i0 + ib + 0];
      As[ib + 1][jr] = w4.y * Ds[i0 + ib + 1];
      As[ib + 2][jr] = w4.z * Ds[i0 + ib + 2];
      As[ib + 3][jr] = w4.w * Ds[i0 + ib + 3];
    }
    // stage Ws: thread -> (k = t&63, i = (t>>6) + rr*4)
    {
      int kc = t & 63;
      int ir = t >> 6;
#pragma unroll
      for (int rr = 0; rr < 4; rr++) {
        int i = ir + rr * 4;
        int k = k0 + kc;
        Ws[i][kc] = (k < INF) ? W1[(size_t)(i0 + i) * INF + k] : 0.f;
      }
    }
    __syncthreads();
#pragma unroll
    for (int ii = 0; ii < TI; ii++) {
      float4 av = *reinterpret_cast<const float4*>(&As[ii][ty * 4]);
      float4 wv = *reinterpret_cast<const float4*>(&Ws[ii][tx * 4]);
      acc[0][0] = fmaf(av.x, wv.x, acc[0][0]);
      acc[0][1] = fmaf(av.x, wv.y, acc[0][1]);
      acc[0][2] = fmaf(av.x, wv.z, acc[0][2]);
      acc[0][3] = fmaf(av.x, wv.w, acc[0][3]);
      acc[1][0] = fmaf(av.y, wv.x, acc[1][0]);
      acc[1][1] = fmaf(av.y, wv.y, acc[1][1]);
      acc[1][2] = fmaf(av.y, wv.z, acc[1][2]);
      acc[1][3] = fmaf(av.y, wv.w, acc[1][3]);
      acc[2][0] = fmaf(av.z, wv.x, acc[2][0]);
      acc[2][1] = fmaf(av.z, wv.y, acc[2][1]);
      acc[2][2] = fmaf(av.z, wv.z, acc[2][2]);
      acc[2][3] = fmaf(av.z, wv.w, acc[2][3]);
      acc[3][0] = fmaf(av.w, wv.x, acc[3][0]);
      acc[3][1] = fmaf(av.w, wv.y, acc[3][1]);
      acc[3][2] = fmaf(av.w, wv.z, acc[3][2]);
      acc[3][3] = fmaf(av.w, wv.w, acc[3][3]);
    }
    __syncthreads();
  }
  // abs-sum over this thread's 4 k, reduce across the 16 tx, atomic into E
#pragma unroll
  for (int r = 0; r < 4; r++) {
    float s = fabsf(acc[r][0]) + fabsf(acc[r][1]) + fabsf(acc[r][2]) + fabsf(acc[r][3]);
    redE[ty * 4 + r][tx] = s;
  }
  __syncthreads();
  if (t < TJ) {
    float s = 0.f;
#pragma unroll
    for (int q = 0; q < 16; q++) s += redE[t][q];
    atomicAdd(&E[(size_t)(j0 + t) * B + b], EPSV * s);
  }
}

// ---------------------------------------------------------------------------
// K4: combine -> zl2, zu2 -> d2, t2, db2 (b-major layouts [b][H2])
// ---------------------------------------------------------------------------
__global__ __launch_bounds__(256) void k4_combine(
    const float* __restrict__ A, const float* __restrict__ Cl,
    const float* __restrict__ Cu, const float* __restrict__ E,
    const float* __restrict__ b2,
    float* __restrict__ d2B, float* __restrict__ t2B, float* __restrict__ db2B)
{
  int idx = blockIdx.x * 256 + threadIdx.x;  // idx = j*B + b
  if (idx >= H2 * B) return;
  int j = idx >> 5, b = idx & 31;
  float a = A[idx], e = E[idx];
  float zl = a - e + Cl[idx];
  float zu = a + e - Cu[idx];
  float d, l;
  if (zl >= 0.f)      { d = 1.f;            l = 0.f; }
  else if (zu > 0.f)  { d = zu / (zu - zl); l = zl;  }
  else                { d = 0.f;            l = 0.f; }
  d2B [(size_t)b * H2 + j] = d;
  t2B [(size_t)b * H2 + j] = d * l;
  db2B[(size_t)b * H2 + j] = d * b2[j];
}

// ---------------------------------------------------------------------------
// K5a: nu2[b][j][i2] = (W3[y_b,i2]-W3[j,i2])*d2[b,i2];  one block per b.
// F[b,j] = (b3[y]-b3[j]) + sum cw*db2 + sum relu(-cw)*t2   (assign)
// ---------------------------------------------------------------------------
__global__ __launch_bounds__(256) void k5a_nu2(
    const float* __restrict__ W3, const float* __restrict__ b3,
    const int* __restrict__ y,
    const float* __restrict__ d2B, const float* __restrict__ t2B,
    const float* __restrict__ db2B,
    float* __restrict__ nu2, float* __restrict__ F)
{
  int b = blockIdx.x;
  int t = threadIdx.x;
  int yb = y[b];
  float accB[NC] = {}, accC[NC] = {};
  for (int i = t; i < H2; i += 256) {
    float d2v = d2B[(size_t)b * H2 + i];
    float t2v = t2B[(size_t)b * H2 + i];
    float dbv = db2B[(size_t)b * H2 + i];
    float wy = W3[(size_t)yb * H2 + i];
#pragma unroll
    for (int j = 0; j < NC; j++) {
      float cw = wy - W3[(size_t)j * H2 + i];
      nu2[((size_t)b * NC + j) * H2 + i] = cw * d2v;
      accB[j] = fmaf(cw, dbv, accB[j]);
      accC[j] = fmaf(fmaxf(-cw, 0.f), t2v, accC[j]);
    }
  }
#pragma unroll
  for (int off = 32; off > 0; off >>= 1) {
#pragma unroll
    for (int j = 0; j < NC; j++) {
      accB[j] += __shfl_down(accB[j], off, 64);
      accC[j] += __shfl_down(accC[j], off, 64);
    }
  }
  __shared__ float red[4][2 * NC];
  int wave = t >> 6, lane = t & 63;
  if (lane == 0) {
#pragma unroll
    for (int j = 0; j < NC; j++) { red[wave][j] = accB[j]; red[wave][NC + j] = accC[j]; }
  }
  __syncthreads();
  if (t < NC) {
    float s = b3[yb] - b3[t];
    for (int w = 0; w < 4; w++) s += red[w][t] + red[w][NC + t];
    F[b * NC + t] = s;  // assign (first writer)
  }
}

// ---------------------------------------------------------------------------
// K5b: h[j][i1] = sum_i2 nu2[b,j,i2]*W2[i2,i1];  nu1f = h*d1.
// Adds (s_nom + cross1) into F.  grid = (4 i1-tiles, 32 b), 1 thread per i1.
// ---------------------------------------------------------------------------
__global__ __launch_bounds__(256) void k5b_h(
    const float* __restrict__ W2, const float* __restrict__ nu2,
    const float* __restrict__ d1B, const float* __restrict__ t1B,
    const float* __restrict__ dnB,
    float* __restrict__ nu1f, float* __restrict__ F)
{
  int b = blockIdx.y;
  int t = threadIdx.x;
  int i1 = blockIdx.x * 256 + t;
  __shared__ float nus[NC][H2];  // 40 KB
  {
    const float* src = nu2 + (size_t)b * NC * H2;
    float* dst = &nus[0][0];
    for (int idx = t; idx < NC * H2; idx += 256) dst[idx] = src[idx];
  }
  __syncthreads();
  float h[NC] = {};
  for (int i2 = 0; i2 < H2; i2 += 4) {
    float w0 = W2[(size_t)(i2 + 0) * H1 + i1];
    float w1 = W2[(size_t)(i2 + 1) * H1 + i1];
    float w2v = W2[(size_t)(i2 + 2) * H1 + i1];
    float w3 = W2[(size_t)(i2 + 3) * H1 + i1];
#pragma unroll
    for (int j = 0; j < NC; j++) {
      float4 nv = *reinterpret_cast<const float4*>(&nus[j][i2]);
      h[j] = fmaf(nv.x, w0, h[j]);
      h[j] = fmaf(nv.y, w1, h[j]);
      h[j] = fmaf(nv.z, w2v, h[j]);
      h[j] = fmaf(nv.w, w3, h[j]);
    }
  }
  float d1v = d1B[(size_t)b * H1 + i1];
  float t1v = t1B[(size_t)b * H1 + i1];
  float dnv = dnB[(size_t)b * H1 + i1];
  float sn[NC], c1[NC];
#pragma unroll
  for (int j = 0; j < NC; j++) {
    float hv = h[j];
    nu1f[((size_t)b * NC + j) * H1 + i1] = hv * d1v;
    sn[j] = hv * dnv;
    c1[j] = fmaxf(-hv, 0.f) * t1v;
  }
#pragma unroll
  for (int off = 32; off > 0; off >>= 1) {
#pragma unroll
    for (int j = 0; j < NC; j++) {
      sn[j] += __shfl_down(sn[j], off, 64);
      c1[j] += __shfl_down(c1[j], off, 64);
    }
  }
  __shared__ float red[4][2 * NC];
  int wave = t >> 6, lane = t & 63;
  if (lane == 0) {
#pragma unroll
    for (int j = 0; j < NC; j++) { red[wave][j] = sn[j]; red[wave][NC + j] = c1[j]; }
  }
  __syncthreads();
  if (t < NC) {
    float s = 0.f;
    for (int w = 0; w < 4; w++) s += red[w][t] + red[w][NC + t];
    atomicAdd(&F[b * NC + t], s);
  }
}

// ---------------------------------------------------------------------------
// K5c: Ef[b,j] = eps * sum_k |sum_i1 nu1f[b,j,i1]*W1[i1,k]|  -> F -= Ef
// grid = (4 k-tiles of 196, 32 b), 1 thread per k (t<196 active).
// ---------------------------------------------------------------------------
__global__ __launch_bounds__(256) void k5c_ef(
    const float* __restrict__ W1, const float* __restrict__ nu1f,
    float* __restrict__ F)
{
  int b = blockIdx.y;
  int t = threadIdx.x;
  int kk = blockIdx.x * 196 + t;
  bool valid = (t < 196);
  int k = valid ? kk : 0;
  __shared__ float nus[NC][H1];  // 40 KB
  {
    const float* src = nu1f + (size_t)b * NC * H1;
    float* dst = &nus[0][0];
    for (int idx = t; idx < NC * H1; idx += 256) dst[idx] = src[idx];
  }
  __syncthreads();
  float acc[NC] = {};
  for (int i1 = 0; i1 < H1; i1 += 4) {
    float a0 = W1[(size_t)(i1 + 0) * INF + k];
    float a1 = W1[(size_t)(i1 + 1) * INF + k];
    float a2 = W1[(size_t)(i1 + 2) * INF + k];
    float a3 = W1[(size_t)(i1 + 3) * INF + k];
#pragma unroll
    for (int j = 0; j < NC; j++) {
      float4 nv = *reinterpret_cast<const float4*>(&nus[j][i1]);
      acc[j] = fmaf(nv.x, a0, acc[j]);
      acc[j] = fmaf(nv.y, a1, acc[j]);
      acc[j] = fmaf(nv.z, a2, acc[j]);
      acc[j] = fmaf(nv.w, a3, acc[j]);
    }
  }
  float e[NC];
#pragma unroll
  for (int j = 0; j < NC; j++) e[j] = valid ? fabsf(acc[j]) : 0.f;
#pragma unroll
  for (int off = 32; off > 0; off >>= 1) {
#pragma unroll
    for (int j = 0; j < NC; j++) e[j] += __shfl_down(e[j], off, 64);
  }
  __shared__ float red[4][NC];
  int wave = t >> 6, lane = t & 63;
  if (lane == 0) {
#pragma unroll
    for (int j = 0; j < NC; j++) red[wave][j] = e[j];
  }
  __syncthreads();
  if (t < NC) {
    float s = 0.f;
    for (int w = 0; w < 4; w++) s += red[w][t];
    atomicAdd(&F[b * NC + t], -EPSV * s);
  }
}

// ---------------------------------------------------------------------------
// K6: out = -F
// ---------------------------------------------------------------------------
__global__ void k6_out(const float* __restrict__ F, float* __restrict__ out) {
  int t = blockIdx.x * 64 + threadIdx.x;
  if (t < B * NC) out[t] = -F[t];
}

// ---------------------------------------------------------------------------
extern "C" void kernel_launch(void* const* d_in, const int* in_sizes, int n_in,
                              void* d_out, int out_size, void* d_ws, size_t ws_size,
                              hipStream_t stream) {
  const float* x  = (const float*)d_in[0];
  const int*   y  = (const int*)  d_in[1];
  const float* W1 = (const float*)d_in[2];
  const float* b1 = (const float*)d_in[3];
  const float* W2 = (const float*)d_in[4];
  const float* b2 = (const float*)d_in[5];
  const float* W3 = (const float*)d_in[6];
  const float* b3 = (const float*)d_in[7];
  float* out = (float*)d_out;
  float* ws  = (float*)d_ws;

  float* d1B  = ws;             // 32768
  float* t1B  = ws + 32768;     // 32768
  float* dnB  = ws + 65536;     // 32768
  float* Aar  = ws + 98304;     // 32768  [j*B+b]
  float* Cl   = ws + 131072;    // 32768
  float* Cu   = ws + 163840;    // 32768
  float* E    = ws + 196608;    // 32768  [j*B+b]  (zeroed)
  float* F    = ws + 229376;    // 320 (pad to 1024)
  float* d2B  = ws + 230400;    // 32768
  float* t2B  = ws + 263168;    // 32768
  float* db2B = ws + 295936;    // 32768
  float* nu2  = ws + 328704;    // 327680
  float* nu1f = ws + 656384;    // 327680  (end 984064 floats ~ 3.75 MB)

  hipMemsetAsync(E, 0, (size_t)H2 * B * sizeof(float), stream);

  k1_layer1<<<H1, 256, 0, stream>>>(x, W1, b1, d1B, t1B, dnB);
  k2_matvec<<<H2, 256, 0, stream>>>(W2, b2, dnB, t1B, Aar, Cl, Cu);
  k3_egemm<<<dim3(13, 16, 32), 256, 0, stream>>>(W2, W1, d1B, E);
  k4_combine<<<(H2 * B + 255) / 256, 256, 0, stream>>>(Aar, Cl, Cu, E, b2, d2B, t2B, db2B);
  k5a_nu2<<<B, 256, 0, stream>>>(W3, b3, y, d2B, t2B, db2B, nu2, F);
  k5b_h<<<dim3(4, B), 256, 0, stream>>>(W2, nu2, d1B, t1B, dnB, nu1f, F);
  k5c_ef<<<dim3(4, B), 256, 0, stream>>>(W1, nu1f, F);
  k6_out<<<5, 64, 0, stream>>>(F, out);
}

// Round 2
// 364.013 us; speedup vs baseline: 2.8832x; 2.8832x over previous
//
#include <hip/hip_runtime.h>
#include <math.h>

#define B    32
#define INF  784
#define H1   1024
#define H2   1024
#define NC   10
#define EPSV 0.1f

typedef __attribute__((ext_vector_type(8))) short short8;
typedef __attribute__((ext_vector_type(4))) float floatx4;

__device__ inline ushort bf16_rne(float f) {
  uint u = __builtin_bit_cast(uint, f);
  u += 0x7FFFu + ((u >> 16) & 1u);
  return (ushort)(u >> 16);
}

// scale a packed pair of bf16 (in dword u) by d0,d1 and repack (round-half-up)
__device__ inline uint scale_pack(uint u, float d0, float d1v) {
  float f0 = __builtin_bit_cast(float, u << 16) * d0;
  float f1 = __builtin_bit_cast(float, u & 0xFFFF0000u) * d1v;
  uint r0 = __builtin_bit_cast(uint, f0) + 0x8000u;
  uint r1 = __builtin_bit_cast(uint, f1) + 0x8000u;
  // result = (r0>>16) | (r1 & 0xFFFF0000): bytes [r0.b2, r0.b3, r1.b2, r1.b3]
  return __builtin_amdgcn_perm(r1, r0, 0x07060302u);
}

// ---------------------------------------------------------------------------
// KP1: W2 (fp32) -> W2bf (bf16), row-major [H2][H1]
// ---------------------------------------------------------------------------
__global__ __launch_bounds__(256) void kp_w2bf(
    const float* __restrict__ W2, ushort* __restrict__ W2bf)
{
  int idx = (blockIdx.x * 256 + threadIdx.x) * 4;
  float4 v = *reinterpret_cast<const float4*>(&W2[idx]);
  ushort4 o;
  o.x = bf16_rne(v.x); o.y = bf16_rne(v.y);
  o.z = bf16_rne(v.z); o.w = bf16_rne(v.w);
  *reinterpret_cast<ushort4*>(&W2bf[idx]) = o;
}

// ---------------------------------------------------------------------------
// KP2: W1 [H1][INF] fp32 -> W1T [1024][H1] bf16 (rows >= INF are zero)
// ---------------------------------------------------------------------------
__global__ __launch_bounds__(256) void kp_w1t(
    const float* __restrict__ W1, ushort* __restrict__ W1T)
{
  __shared__ float T[64][65];
  int i0 = blockIdx.y * 64, k0 = blockIdx.x * 64;
  int t = threadIdx.x;
  int c = t & 63;
  int r4 = t >> 6;
  for (int r = r4; r < 64; r += 4) {
    int k = k0 + c;
    T[r][c] = (k < INF) ? W1[(size_t)(i0 + r) * INF + k] : 0.f;
  }
  __syncthreads();
  for (int r = r4; r < 64; r += 4) {
    W1T[(size_t)(k0 + r) * H1 + i0 + c] = bf16_rne(T[c][r]);
  }
}

// ---------------------------------------------------------------------------
// K1: layer-1.  One block per i (row of W1).
// ---------------------------------------------------------------------------
__global__ __launch_bounds__(256) void k1_layer1(
    const float* __restrict__ x, const float* __restrict__ W1,
    const float* __restrict__ b1,
    float* __restrict__ d1B, float* __restrict__ t1B, float* __restrict__ dnB)
{
  int i = blockIdx.x;
  int t = threadIdx.x;
  const float* w = W1 + (size_t)i * INF;
  float acc[B];
#pragma unroll
  for (int b = 0; b < B; b++) acc[b] = 0.f;
  float wabs = 0.f;
  for (int k = t; k < INF; k += 256) {
    float wv = w[k];
    wabs += fabsf(wv);
#pragma unroll
    for (int b = 0; b < B; b++) acc[b] = fmaf(x[b * INF + k], wv, acc[b]);
  }
#pragma unroll
  for (int off = 32; off > 0; off >>= 1) {
#pragma unroll
    for (int b = 0; b < B; b++) acc[b] += __shfl_down(acc[b], off, 64);
    wabs += __shfl_down(wabs, off, 64);
  }
  __shared__ float red[4][B + 1];
  int wave = t >> 6, lane = t & 63;
  if (lane == 0) {
#pragma unroll
    for (int b = 0; b < B; b++) red[wave][b] = acc[b];
    red[wave][B] = wabs;
  }
  __syncthreads();
  if (t < B) {
    float s = red[0][t] + red[1][t] + red[2][t] + red[3][t];
    float r = EPSV * (red[0][B] + red[1][B] + red[2][B] + red[3][B]);
    float nom = s + b1[i];
    float zl = nom - r, zu = nom + r;
    float d, l;
    if (zl >= 0.f)      { d = 1.f;            l = 0.f; }
    else if (zu > 0.f)  { d = zu / (zu - zl); l = zl;  }
    else                { d = 0.f;            l = 0.f; }
    d1B[(size_t)t * H1 + i] = d;
    t1B[(size_t)t * H1 + i] = d * l;
    dnB[(size_t)t * H1 + i] = d * nom;
  }
}

// ---------------------------------------------------------------------------
// K2: A / crossl / crossu matvecs.  One block per j (row of W2).
// ---------------------------------------------------------------------------
__global__ __launch_bounds__(256) void k2_matvec(
    const float* __restrict__ W2, const float* __restrict__ b2,
    const float* __restrict__ dnB, const float* __restrict__ t1B,
    float* __restrict__ A, float* __restrict__ Cl, float* __restrict__ Cu)
{
  int j = blockIdx.x;
  int t = threadIdx.x;
  int wave = t >> 6, lane = t & 63;
  int b0 = wave * 8;
  float aA[8] = {}, aCl[8] = {}, aCu[8] = {};
  const float* __restrict__ w2 = W2 + (size_t)j * H1;
  for (int i = lane; i < H1; i += 64) {
    float wv = w2[i];
    float wp = fmaxf(wv, 0.f), wn = fmaxf(-wv, 0.f);
#pragma unroll
    for (int r = 0; r < 8; r++) {
      float dv = dnB[(size_t)(b0 + r) * H1 + i];
      float tv = t1B[(size_t)(b0 + r) * H1 + i];
      aA[r]  = fmaf(wv, dv, aA[r]);
      aCl[r] = fmaf(wn, tv, aCl[r]);
      aCu[r] = fmaf(wp, tv, aCu[r]);
    }
  }
#pragma unroll
  for (int off = 32; off > 0; off >>= 1) {
#pragma unroll
    for (int r = 0; r < 8; r++) {
      aA[r]  += __shfl_down(aA[r],  off, 64);
      aCl[r] += __shfl_down(aCl[r], off, 64);
      aCu[r] += __shfl_down(aCu[r], off, 64);
    }
  }
  if (lane == 0) {
    float bj = b2[j];
#pragma unroll
    for (int r = 0; r < 8; r++) {
      A [(size_t)j * B + b0 + r] = aA[r] + bj;
      Cl[(size_t)j * B + b0 + r] = aCl[r];
      Cu[(size_t)j * B + b0 + r] = aCu[r];
    }
  }
}

// ---------------------------------------------------------------------------
// K3 (MFMA): E[j,b] = eps * sum_k | sum_i W2[j,i]*d1[b,i]*W1[i,k] |
// bf16 MFMA 16x16x32.  Block: 128j x 256k, BK=32.  4 waves: wy=j-half, wx=k-half.
// grid = (4 ktiles, 8 jtiles, 32 b)
// ---------------------------------------------------------------------------
#define TKK 256
__global__ __launch_bounds__(256, 2) void k3_mfma(
    const ushort* __restrict__ W2bf, const ushort* __restrict__ W1T,
    const float* __restrict__ d1B, float* __restrict__ E)
{
  int b  = blockIdx.z;
  int j0 = blockIdx.y * 128;
  int k0 = blockIdx.x * TKK;
  int t  = threadIdx.x;
  int w  = t >> 6, lane = t & 63;
  int wy = w >> 1, wx = w & 1;
  int quad = lane >> 4, l15 = lane & 15;

  __shared__ ushort As[128][40];   // padded: 80B row stride (16B-aligned, 2-way banks)
  __shared__ ushort Bs[TKK][40];
  __shared__ float  Ds[H1];

  for (int idx = t; idx < H1; idx += 256) Ds[idx] = d1B[(size_t)b * H1 + idx];

  floatx4 acc[4][8];
#pragma unroll
  for (int a = 0; a < 4; a++)
#pragma unroll
    for (int c = 0; c < 8; c++) acc[a][c] = (floatx4){0.f, 0.f, 0.f, 0.f};

  int jr = t >> 1, hf = t & 1;
  const ushort* w2row = W2bf + (size_t)(j0 + jr) * H1 + hf * 16;
  const ushort* w1row = W1T + (size_t)(k0 + t) * H1;

  __syncthreads();  // Ds ready

  for (int i0 = 0; i0 < H1; i0 += 32) {
    // ---- stage A: 128j x 32i, scaled by d1 ----
#pragma unroll
    for (int c = 0; c < 2; c++) {
      uint4 ra = *reinterpret_cast<const uint4*>(w2row + i0 + c * 8);
      float4 dv0 = *reinterpret_cast<const float4*>(&Ds[i0 + hf * 16 + c * 8]);
      float4 dv1 = *reinterpret_cast<const float4*>(&Ds[i0 + hf * 16 + c * 8 + 4]);
      uint4 o;
      o.x = scale_pack(ra.x, dv0.x, dv0.y);
      o.y = scale_pack(ra.y, dv0.z, dv0.w);
      o.z = scale_pack(ra.z, dv1.x, dv1.y);
      o.w = scale_pack(ra.w, dv1.z, dv1.w);
      *reinterpret_cast<uint4*>(&As[jr][hf * 16 + c * 8]) = o;
    }
    // ---- stage B: 256k x 32i, plain copy of W1T (B^T layout) ----
#pragma unroll
    for (int c = 0; c < 4; c++) {
      uint4 rb = *reinterpret_cast<const uint4*>(w1row + i0 + c * 8);
      *reinterpret_cast<uint4*>(&Bs[t][c * 8]) = rb;
    }
    __syncthreads();

    short8 af[4], bfr[8];
#pragma unroll
    for (int mj = 0; mj < 4; mj++)
      af[mj] = *reinterpret_cast<const short8*>(&As[wy * 64 + mj * 16 + l15][quad * 8]);
#pragma unroll
    for (int nk = 0; nk < 8; nk++)
      bfr[nk] = *reinterpret_cast<const short8*>(&Bs[wx * 128 + nk * 16 + l15][quad * 8]);
#pragma unroll
    for (int mj = 0; mj < 4; mj++)
#pragma unroll
      for (int nk = 0; nk < 8; nk++)
        acc[mj][nk] = __builtin_amdgcn_mfma_f32_16x16x32_bf16(af[mj], bfr[nk], acc[mj][nk], 0, 0, 0);
    __syncthreads();
  }

  // epilogue: abs-sum over k (cols = lane&15 groups), atomic into E
#pragma unroll
  for (int mj = 0; mj < 4; mj++) {
#pragma unroll
    for (int r = 0; r < 4; r++) {
      float s = 0.f;
#pragma unroll
      for (int nk = 0; nk < 8; nk++) s += fabsf(acc[mj][nk][r]);
      s += __shfl_xor(s, 1, 64);
      s += __shfl_xor(s, 2, 64);
      s += __shfl_xor(s, 4, 64);
      s += __shfl_xor(s, 8, 64);
      if (l15 == 0) {
        int j = j0 + wy * 64 + mj * 16 + quad * 4 + r;
        atomicAdd(&E[(size_t)j * B + b], EPSV * s);
      }
    }
  }
}

// ---------------------------------------------------------------------------
// K4: combine -> zl2, zu2 -> d2, t2, db2 (b-major layouts [b][H2])
// ---------------------------------------------------------------------------
__global__ __launch_bounds__(256) void k4_combine(
    const float* __restrict__ A, const float* __restrict__ Cl,
    const float* __restrict__ Cu, const float* __restrict__ E,
    const float* __restrict__ b2,
    float* __restrict__ d2B, float* __restrict__ t2B, float* __restrict__ db2B)
{
  int idx = blockIdx.x * 256 + threadIdx.x;  // idx = j*B + b
  if (idx >= H2 * B) return;
  int j = idx >> 5, b = idx & 31;
  float a = A[idx], e = E[idx];
  float zl = a - e + Cl[idx];
  float zu = a + e - Cu[idx];
  float d, l;
  if (zl >= 0.f)      { d = 1.f;            l = 0.f; }
  else if (zu > 0.f)  { d = zu / (zu - zl); l = zl;  }
  else                { d = 0.f;            l = 0.f; }
  d2B [(size_t)b * H2 + j] = d;
  t2B [(size_t)b * H2 + j] = d * l;
  db2B[(size_t)b * H2 + j] = d * b2[j];
}

// ---------------------------------------------------------------------------
// K5a: nu2[b][j][i2] = (W3[y_b,i2]-W3[j,i2])*d2[b,i2];  one block per b.
// ---------------------------------------------------------------------------
__global__ __launch_bounds__(256) void k5a_nu2(
    const float* __restrict__ W3, const float* __restrict__ b3,
    const int* __restrict__ y,
    const float* __restrict__ d2B, const float* __restrict__ t2B,
    const float* __restrict__ db2B,
    float* __restrict__ nu2, float* __restrict__ F)
{
  int b = blockIdx.x;
  int t = threadIdx.x;
  int yb = y[b];
  float accB[NC] = {}, accC[NC] = {};
  for (int i = t; i < H2; i += 256) {
    float d2v = d2B[(size_t)b * H2 + i];
    float t2v = t2B[(size_t)b * H2 + i];
    float dbv = db2B[(size_t)b * H2 + i];
    float wy = W3[(size_t)yb * H2 + i];
#pragma unroll
    for (int j = 0; j < NC; j++) {
      float cw = wy - W3[(size_t)j * H2 + i];
      nu2[((size_t)b * NC + j) * H2 + i] = cw * d2v;
      accB[j] = fmaf(cw, dbv, accB[j]);
      accC[j] = fmaf(fmaxf(-cw, 0.f), t2v, accC[j]);
    }
  }
#pragma unroll
  for (int off = 32; off > 0; off >>= 1) {
#pragma unroll
    for (int j = 0; j < NC; j++) {
      accB[j] += __shfl_down(accB[j], off, 64);
      accC[j] += __shfl_down(accC[j], off, 64);
    }
  }
  __shared__ float red[4][2 * NC];
  int wave = t >> 6, lane = t & 63;
  if (lane == 0) {
#pragma unroll
    for (int j = 0; j < NC; j++) { red[wave][j] = accB[j]; red[wave][NC + j] = accC[j]; }
  }
  __syncthreads();
  if (t < NC) {
    float s = b3[yb] - b3[t];
    for (int w = 0; w < 4; w++) s += red[w][t] + red[w][NC + t];
    F[b * NC + t] = s;  // assign (first writer)
  }
}

// ---------------------------------------------------------------------------
// K5b: h[j][i1] = sum_i2 nu2[b,j,i2]*W2[i2,i1];  nu1f = h*d1.
// ---------------------------------------------------------------------------
__global__ __launch_bounds__(256) void k5b_h(
    const float* __restrict__ W2, const float* __restrict__ nu2,
    const float* __restrict__ d1B, const float* __restrict__ t1B,
    const float* __restrict__ dnB,
    float* __restrict__ nu1f, float* __restrict__ F)
{
  int b = blockIdx.y;
  int t = threadIdx.x;
  int i1 = blockIdx.x * 256 + t;
  __shared__ float nus[NC][H2];  // 40 KB
  {
    const float* src = nu2 + (size_t)b * NC * H2;
    float* dst = &nus[0][0];
    for (int idx = t; idx < NC * H2; idx += 256) dst[idx] = src[idx];
  }
  __syncthreads();
  float h[NC] = {};
  for (int i2 = 0; i2 < H2; i2 += 4) {
    float w0 = W2[(size_t)(i2 + 0) * H1 + i1];
    float w1 = W2[(size_t)(i2 + 1) * H1 + i1];
    float w2v = W2[(size_t)(i2 + 2) * H1 + i1];
    float w3 = W2[(size_t)(i2 + 3) * H1 + i1];
#pragma unroll
    for (int j = 0; j < NC; j++) {
      float4 nv = *reinterpret_cast<const float4*>(&nus[j][i2]);
      h[j] = fmaf(nv.x, w0, h[j]);
      h[j] = fmaf(nv.y, w1, h[j]);
      h[j] = fmaf(nv.z, w2v, h[j]);
      h[j] = fmaf(nv.w, w3, h[j]);
    }
  }
  float d1v = d1B[(size_t)b * H1 + i1];
  float t1v = t1B[(size_t)b * H1 + i1];
  float dnv = dnB[(size_t)b * H1 + i1];
  float sn[NC], c1[NC];
#pragma unroll
  for (int j = 0; j < NC; j++) {
    float hv = h[j];
    nu1f[((size_t)b * NC + j) * H1 + i1] = hv * d1v;
    sn[j] = hv * dnv;
    c1[j] = fmaxf(-hv, 0.f) * t1v;
  }
#pragma unroll
  for (int off = 32; off > 0; off >>= 1) {
#pragma unroll
    for (int j = 0; j < NC; j++) {
      sn[j] += __shfl_down(sn[j], off, 64);
      c1[j] += __shfl_down(c1[j], off, 64);
    }
  }
  __shared__ float red[4][2 * NC];
  int wave = t >> 6, lane = t & 63;
  if (lane == 0) {
#pragma unroll
    for (int j = 0; j < NC; j++) { red[wave][j] = sn[j]; red[wave][NC + j] = c1[j]; }
  }
  __syncthreads();
  if (t < NC) {
    float s = 0.f;
    for (int w = 0; w < 4; w++) s += red[w][t] + red[w][NC + t];
    atomicAdd(&F[b * NC + t], s);
  }
}

// ---------------------------------------------------------------------------
// K5c: Ef[b,j] = eps * sum_k |sum_i1 nu1f[b,j,i1]*W1[i1,k]|  -> F -= Ef
// ---------------------------------------------------------------------------
__global__ __launch_bounds__(256) void k5c_ef(
    const float* __restrict__ W1, const float* __restrict__ nu1f,
    float* __restrict__ F)
{
  int b = blockIdx.y;
  int t = threadIdx.x;
  int kk = blockIdx.x * 196 + t;
  bool valid = (t < 196);
  int k = valid ? kk : 0;
  __shared__ float nus[NC][H1];  // 40 KB
  {
    const float* src = nu1f + (size_t)b * NC * H1;
    float* dst = &nus[0][0];
    for (int idx = t; idx < NC * H1; idx += 256) dst[idx] = src[idx];
  }
  __syncthreads();
  float acc[NC] = {};
  for (int i1 = 0; i1 < H1; i1 += 4) {
    float a0 = W1[(size_t)(i1 + 0) * INF + k];
    float a1 = W1[(size_t)(i1 + 1) * INF + k];
    float a2 = W1[(size_t)(i1 + 2) * INF + k];
    float a3 = W1[(size_t)(i1 + 3) * INF + k];
#pragma unroll
    for (int j = 0; j < NC; j++) {
      float4 nv = *reinterpret_cast<const float4*>(&nus[j][i1]);
      acc[j] = fmaf(nv.x, a0, acc[j]);
      acc[j] = fmaf(nv.y, a1, acc[j]);
      acc[j] = fmaf(nv.z, a2, acc[j]);
      acc[j] = fmaf(nv.w, a3, acc[j]);
    }
  }
  float e[NC];
#pragma unroll
  for (int j = 0; j < NC; j++) e[j] = valid ? fabsf(acc[j]) : 0.f;
#pragma unroll
  for (int off = 32; off > 0; off >>= 1) {
#pragma unroll
    for (int j = 0; j < NC; j++) e[j] += __shfl_down(e[j], off, 64);
  }
  __shared__ float red[4][NC];
  int wave = t >> 6, lane = t & 63;
  if (lane == 0) {
#pragma unroll
    for (int j = 0; j < NC; j++) red[wave][j] = e[j];
  }
  __syncthreads();
  if (t < NC) {
    float s = 0.f;
    for (int w = 0; w < 4; w++) s += red[w][t];
    atomicAdd(&F[b * NC + t], -EPSV * s);
  }
}

// ---------------------------------------------------------------------------
// K6: out = -F
// ---------------------------------------------------------------------------
__global__ void k6_out(const float* __restrict__ F, float* __restrict__ out) {
  int t = blockIdx.x * 64 + threadIdx.x;
  if (t < B * NC) out[t] = -F[t];
}

// ---------------------------------------------------------------------------
extern "C" void kernel_launch(void* const* d_in, const int* in_sizes, int n_in,
                              void* d_out, int out_size, void* d_ws, size_t ws_size,
                              hipStream_t stream) {
  const float* x  = (const float*)d_in[0];
  const int*   y  = (const int*)  d_in[1];
  const float* W1 = (const float*)d_in[2];
  const float* b1 = (const float*)d_in[3];
  const float* W2 = (const float*)d_in[4];
  const float* b2 = (const float*)d_in[5];
  const float* W3 = (const float*)d_in[6];
  const float* b3 = (const float*)d_in[7];
  float* out = (float*)d_out;
  float* ws  = (float*)d_ws;

  float* d1B  = ws;             // 32768
  float* t1B  = ws + 32768;     // 32768
  float* dnB  = ws + 65536;     // 32768
  float* Aar  = ws + 98304;     // 32768  [j*B+b]
  float* Cl   = ws + 131072;    // 32768
  float* Cu   = ws + 163840;    // 32768
  float* E    = ws + 196608;    // 32768  [j*B+b]  (zeroed)
  float* F    = ws + 229376;    // 320 (pad to 1024)
  float* d2B  = ws + 230400;    // 32768
  float* t2B  = ws + 263168;    // 32768
  float* db2B = ws + 295936;    // 32768
  float* nu2  = ws + 328704;    // 327680
  float* nu1f = ws + 656384;    // 327680
  ushort* W2bf = (ushort*)(ws + 984064);            // 1M ushort = 2 MB
  ushort* W1T  = (ushort*)(ws + 984064 + 524288);   // 1M ushort = 2 MB (1024x1024, zero-padded rows)

  hipMemsetAsync(E, 0, (size_t)H2 * B * sizeof(float), stream);

  kp_w2bf<<<H2 * H1 / (256 * 4), 256, 0, stream>>>(W2, W2bf);
  kp_w1t<<<dim3(16, 16), 256, 0, stream>>>(W1, W1T);
  k1_layer1<<<H1, 256, 0, stream>>>(x, W1, b1, d1B, t1B, dnB);
  k3_mfma<<<dim3(4, 8, 32), 256, 0, stream>>>(W2bf, W1T, d1B, E);
  k2_matvec<<<H2, 256, 0, stream>>>(W2, b2, dnB, t1B, Aar, Cl, Cu);
  k4_combine<<<(H2 * B + 255) / 256, 256, 0, stream>>>(Aar, Cl, Cu, E, b2, d2B, t2B, db2B);
  k5a_nu2<<<B, 256, 0, stream>>>(W3, b3, y, d2B, t2B, db2B, nu2, F);
  k5b_h<<<dim3(4, B), 256, 0, stream>>>(W2, nu2, d1B, t1B, dnB, nu1f, F);
  k5c_ef<<<dim3(4, B), 256, 0, stream>>>(W1, nu1f, F);
  k6_out<<<5, 64, 0, stream>>>(F, out);
}

// Round 3
// 331.633 us; speedup vs baseline: 3.1647x; 1.0976x over previous
//
#include <hip/hip_runtime.h>
#include <math.h>

#define B    32
#define INF  784
#define H1   1024
#define H2   1024
#define NC   10
#define EPSV 0.1f

typedef __attribute__((ext_vector_type(8))) short short8;
typedef __attribute__((ext_vector_type(4))) float floatx4;

__device__ inline ushort bf16_rne(float f) {
  uint u = __builtin_bit_cast(uint, f);
  u += 0x7FFFu + ((u >> 16) & 1u);
  return (ushort)(u >> 16);
}
__device__ inline uint pack2(float a, float b) {
  return (uint)bf16_rne(a) | ((uint)bf16_rne(b) << 16);
}
// scale a packed pair of bf16 (in dword u) by d0,d1 and repack
__device__ inline uint scale_pack(uint u, float d0, float d1v) {
  float f0 = __builtin_bit_cast(float, u << 16) * d0;
  float f1 = __builtin_bit_cast(float, u & 0xFFFF0000u) * d1v;
  uint r0 = __builtin_bit_cast(uint, f0) + 0x8000u;
  uint r1 = __builtin_bit_cast(uint, f1) + 0x8000u;
  return __builtin_amdgcn_perm(r1, r0, 0x07060302u);
}

// ---------------------------------------------------------------------------
// K_PRE: merged preprocessing.
//  blocks [0,64):   W2F fragment pack.  jt = bid.
//     W2F[((c*64+jt)*64+lane)*8+e] = bf16(W2[jt*16+l15][c*32+quad*8+e])
//  blocks [64,113): W1F fragment pack.  mt = bid-64.  (m-dim = k, 49 tiles, no pad)
//     W1F[((c*49+mt)*64+lane)*8+e] = bf16(W1[(c*32+quad*8+e)*INF + mt*16+l15])
//  blocks [113,1137): layer-1 row i = bid-113 (nom1, r1 -> d1,t1,dn, b-major)
// ---------------------------------------------------------------------------
__global__ __launch_bounds__(256) void k_pre(
    const float* __restrict__ x, const float* __restrict__ W1,
    const float* __restrict__ b1, const float* __restrict__ W2,
    ushort* __restrict__ W1F, ushort* __restrict__ W2F,
    float* __restrict__ d1B, float* __restrict__ t1B, float* __restrict__ dnB)
{
  __shared__ float red[4][B + 1];
  int bid = blockIdx.x;
  int t = threadIdx.x;
  if (bid < 64) {
    int jt = bid;
    int lane = t & 63, c0 = t >> 6;
    int l15 = lane & 15, quad = lane >> 4;
    for (int c = c0; c < 32; c += 4) {
      const float* src = &W2[(size_t)(jt * 16 + l15) * H1 + c * 32 + quad * 8];
      float4 v0 = *reinterpret_cast<const float4*>(src);
      float4 v1 = *reinterpret_cast<const float4*>(src + 4);
      uint4 o;
      o.x = pack2(v0.x, v0.y); o.y = pack2(v0.z, v0.w);
      o.z = pack2(v1.x, v1.y); o.w = pack2(v1.z, v1.w);
      *reinterpret_cast<uint4*>(&W2F[((size_t)(c * 64 + jt) * 64 + lane) * 8]) = o;
    }
  } else if (bid < 113) {
    int mt = bid - 64;
    int lane = t & 63, c0 = t >> 6;
    int l15 = lane & 15, quad = lane >> 4;
    int col = mt * 16 + l15;
    for (int c = c0; c < 32; c += 4) {
      int r0 = c * 32 + quad * 8;
      float f[8];
#pragma unroll
      for (int e = 0; e < 8; e++) f[e] = W1[(size_t)(r0 + e) * INF + col];
      uint4 o;
      o.x = pack2(f[0], f[1]); o.y = pack2(f[2], f[3]);
      o.z = pack2(f[4], f[5]); o.w = pack2(f[6], f[7]);
      *reinterpret_cast<uint4*>(&W1F[((size_t)(c * 49 + mt) * 64 + lane) * 8]) = o;
    }
  } else {
    int i = bid - 113;
    const float* w = W1 + (size_t)i * INF;
    float acc[B];
#pragma unroll
    for (int b = 0; b < B; b++) acc[b] = 0.f;
    float wabs = 0.f;
    for (int k = t; k < INF; k += 256) {
      float wv = w[k];
      wabs += fabsf(wv);
#pragma unroll
      for (int b = 0; b < B; b++) acc[b] = fmaf(x[b * INF + k], wv, acc[b]);
    }
#pragma unroll
    for (int off = 32; off > 0; off >>= 1) {
#pragma unroll
      for (int b = 0; b < B; b++) acc[b] += __shfl_down(acc[b], off, 64);
      wabs += __shfl_down(wabs, off, 64);
    }
    int wave = t >> 6, lane = t & 63;
    if (lane == 0) {
#pragma unroll
      for (int b = 0; b < B; b++) red[wave][b] = acc[b];
      red[wave][B] = wabs;
    }
    __syncthreads();
    if (t < B) {
      float s = red[0][t] + red[1][t] + red[2][t] + red[3][t];
      float r = EPSV * (red[0][B] + red[1][B] + red[2][B] + red[3][B]);
      float nom = s + b1[i];
      float zl = nom - r, zu = nom + r;
      float d, l;
      if (zl >= 0.f)      { d = 1.f;            l = 0.f; }
      else if (zu > 0.f)  { d = zu / (zu - zl); l = zl;  }
      else                { d = 0.f;            l = 0.f; }
      d1B[(size_t)t * H1 + i] = d;
      t1B[(size_t)t * H1 + i] = d * l;
      dnB[(size_t)t * H1 + i] = d * nom;
    }
  }
}

// ---------------------------------------------------------------------------
// K3 v3: E[j,b] = eps * sum_k | sum_i W1[i,k] * (W2[j,i]*d1[b,i]) |
// MFMA 16x16x32, A-side = W1F (m = k-dim, 784 = 49 tiles exact, no padding),
// B-side = W2F scaled in-register by d1.  NO LDS in K-loop, no barriers:
// fragments loaded straight from L2-resident fragment-ordered arrays, with
// 2-deep register double buffering (AITER-style vmcnt pipelining).
// Block: 4 waves, per wave 7 m-tiles x 4 n-tiles (112k x 64j), block n = 256j.
// grid = (7, 4, 32b)
// ---------------------------------------------------------------------------
#define K3_LOAD(c, A, Bv) do {                                                  \
  _Pragma("unroll")                                                             \
  for (int mi = 0; mi < 7; mi++)                                                \
    A[mi] = *reinterpret_cast<const uint4*>(aBase + (size_t)(c) * 25088 + mi * 512); \
  _Pragma("unroll")                                                             \
  for (int ni = 0; ni < 4; ni++)                                                \
    Bv[ni] = *reinterpret_cast<const uint4*>(bBase + (size_t)(c) * 32768 + ni * 512); \
} while (0)

#define K3_COMP(c, A, Bv) do {                                                  \
  float4 dv0 = *reinterpret_cast<const float4*>(&Ds[(c) * 32 + quad * 8]);      \
  float4 dv1 = *reinterpret_cast<const float4*>(&Ds[(c) * 32 + quad * 8 + 4]);  \
  short8 bfr[4];                                                                \
  _Pragma("unroll")                                                             \
  for (int ni = 0; ni < 4; ni++) {                                              \
    uint4 sb;                                                                   \
    sb.x = scale_pack(Bv[ni].x, dv0.x, dv0.y);                                  \
    sb.y = scale_pack(Bv[ni].y, dv0.z, dv0.w);                                  \
    sb.z = scale_pack(Bv[ni].z, dv1.x, dv1.y);                                  \
    sb.w = scale_pack(Bv[ni].w, dv1.z, dv1.w);                                  \
    bfr[ni] = __builtin_bit_cast(short8, sb);                                   \
  }                                                                             \
  _Pragma("unroll")                                                             \
  for (int mi = 0; mi < 7; mi++) {                                              \
    short8 af = __builtin_bit_cast(short8, A[mi]);                              \
    _Pragma("unroll")                                                           \
    for (int ni = 0; ni < 4; ni++)                                              \
      acc[mi][ni] = __builtin_amdgcn_mfma_f32_16x16x32_bf16(af, bfr[ni], acc[mi][ni], 0, 0, 0); \
  }                                                                             \
} while (0)

__global__ __launch_bounds__(256, 1) void k3_mfma(
    const ushort* __restrict__ W1F, const ushort* __restrict__ W2F,
    const float* __restrict__ d1B, float* __restrict__ E)
{
  int b = blockIdx.z;
  int t = threadIdx.x, w = t >> 6, lane = t & 63;
  int quad = lane >> 4, l15 = lane & 15;
  int mt0 = blockIdx.x * 7;
  int jt0 = blockIdx.y * 16 + w * 4;

  __shared__ float Ds[H1];
  for (int idx = t; idx < H1; idx += 256) Ds[idx] = d1B[(size_t)b * H1 + idx];
  __syncthreads();

  const ushort* aBase = W1F + ((size_t)mt0 * 64 + lane) * 8;  // + c*49*512
  const ushort* bBase = W2F + ((size_t)jt0 * 64 + lane) * 8;  // + c*64*512

  floatx4 acc[7][4];
#pragma unroll
  for (int mi = 0; mi < 7; mi++)
#pragma unroll
    for (int ni = 0; ni < 4; ni++) acc[mi][ni] = (floatx4){0.f, 0.f, 0.f, 0.f};

  uint4 a0[7], b0[4], a1[7], b1v[4];
  K3_LOAD(0, a0, b0);
  K3_LOAD(1, a1, b1v);
  for (int c = 0; c < 30; c += 2) {
    K3_COMP(c, a0, b0);
    K3_LOAD(c + 2, a0, b0);
    K3_COMP(c + 1, a1, b1v);
    if (c + 3 < 32) K3_LOAD(c + 3, a1, b1v);
  }
  K3_COMP(30, a0, b0);
  K3_COMP(31, a1, b1v);

  // epilogue: C row = k (quad*4+r within tile mi), col = j (l15 within tile ni)
#pragma unroll
  for (int ni = 0; ni < 4; ni++) {
    float s = 0.f;
#pragma unroll
    for (int mi = 0; mi < 7; mi++)
#pragma unroll
      for (int r = 0; r < 4; r++) s += fabsf(acc[mi][ni][r]);
    s += __shfl_xor(s, 16, 64);
    s += __shfl_xor(s, 32, 64);
    if (lane < 16) {
      int j = (jt0 + ni) * 16 + l15;
      atomicAdd(&E[(size_t)j * B + b], EPSV * s);
    }
  }
}

// ---------------------------------------------------------------------------
// K2: A / crossl / crossu matvecs.  One block per j (row of W2).
// ---------------------------------------------------------------------------
__global__ __launch_bounds__(256) void k2_matvec(
    const float* __restrict__ W2, const float* __restrict__ b2,
    const float* __restrict__ dnB, const float* __restrict__ t1B,
    float* __restrict__ A, float* __restrict__ Cl, float* __restrict__ Cu)
{
  int j = blockIdx.x;
  int t = threadIdx.x;
  int wave = t >> 6, lane = t & 63;
  int b0 = wave * 8;
  float aA[8] = {}, aCl[8] = {}, aCu[8] = {};
  const float* __restrict__ w2 = W2 + (size_t)j * H1;
  for (int i = lane; i < H1; i += 64) {
    float wv = w2[i];
    float wp = fmaxf(wv, 0.f), wn = fmaxf(-wv, 0.f);
#pragma unroll
    for (int r = 0; r < 8; r++) {
      float dv = dnB[(size_t)(b0 + r) * H1 + i];
      float tv = t1B[(size_t)(b0 + r) * H1 + i];
      aA[r]  = fmaf(wv, dv, aA[r]);
      aCl[r] = fmaf(wn, tv, aCl[r]);
      aCu[r] = fmaf(wp, tv, aCu[r]);
    }
  }
#pragma unroll
  for (int off = 32; off > 0; off >>= 1) {
#pragma unroll
    for (int r = 0; r < 8; r++) {
      aA[r]  += __shfl_down(aA[r],  off, 64);
      aCl[r] += __shfl_down(aCl[r], off, 64);
      aCu[r] += __shfl_down(aCu[r], off, 64);
    }
  }
  if (lane == 0) {
    float bj = b2[j];
#pragma unroll
    for (int r = 0; r < 8; r++) {
      A [(size_t)j * B + b0 + r] = aA[r] + bj;
      Cl[(size_t)j * B + b0 + r] = aCl[r];
      Cu[(size_t)j * B + b0 + r] = aCu[r];
    }
  }
}

// ---------------------------------------------------------------------------
// K4: combine -> zl2, zu2 -> d2, t2, db2 (b-major layouts [b][H2])
// ---------------------------------------------------------------------------
__global__ __launch_bounds__(256) void k4_combine(
    const float* __restrict__ A, const float* __restrict__ Cl,
    const float* __restrict__ Cu, const float* __restrict__ E,
    const float* __restrict__ b2,
    float* __restrict__ d2B, float* __restrict__ t2B, float* __restrict__ db2B)
{
  int idx = blockIdx.x * 256 + threadIdx.x;  // idx = j*B + b
  if (idx >= H2 * B) return;
  int j = idx >> 5, b = idx & 31;
  float a = A[idx], e = E[idx];
  float zl = a - e + Cl[idx];
  float zu = a + e - Cu[idx];
  float d, l;
  if (zl >= 0.f)      { d = 1.f;            l = 0.f; }
  else if (zu > 0.f)  { d = zu / (zu - zl); l = zl;  }
  else                { d = 0.f;            l = 0.f; }
  d2B [(size_t)b * H2 + j] = d;
  t2B [(size_t)b * H2 + j] = d * l;
  db2B[(size_t)b * H2 + j] = d * b2[j];
}

// ---------------------------------------------------------------------------
// K5a: nu2[b][j][i2] = (W3[y_b,i2]-W3[j,i2])*d2[b,i2]
// grid (4 i-slices, 32 b) for occupancy; F accumulated atomically (pre-zeroed).
// ---------------------------------------------------------------------------
__global__ __launch_bounds__(256) void k5a_nu2(
    const float* __restrict__ W3, const float* __restrict__ b3,
    const int* __restrict__ y,
    const float* __restrict__ d2B, const float* __restrict__ t2B,
    const float* __restrict__ db2B,
    float* __restrict__ nu2, float* __restrict__ F)
{
  int b = blockIdx.y;
  int t = threadIdx.x;
  int i = blockIdx.x * 256 + t;
  int yb = y[b];
  float d2v = d2B[(size_t)b * H2 + i];
  float t2v = t2B[(size_t)b * H2 + i];
  float dbv = db2B[(size_t)b * H2 + i];
  float wy = W3[(size_t)yb * H2 + i];
  float accB[NC], accC[NC];
#pragma unroll
  for (int j = 0; j < NC; j++) {
    float cw = wy - W3[(size_t)j * H2 + i];
    nu2[((size_t)b * NC + j) * H2 + i] = cw * d2v;
    accB[j] = cw * dbv;
    accC[j] = fmaxf(-cw, 0.f) * t2v;
  }
#pragma unroll
  for (int off = 32; off > 0; off >>= 1) {
#pragma unroll
    for (int j = 0; j < NC; j++) {
      accB[j] += __shfl_down(accB[j], off, 64);
      accC[j] += __shfl_down(accC[j], off, 64);
    }
  }
  __shared__ float red[4][2 * NC];
  int wave = t >> 6, lane = t & 63;
  if (lane == 0) {
#pragma unroll
    for (int j = 0; j < NC; j++) { red[wave][j] = accB[j]; red[wave][NC + j] = accC[j]; }
  }
  __syncthreads();
  if (t < NC) {
    float s = 0.f;
    for (int w = 0; w < 4; w++) s += red[w][t] + red[w][NC + t];
    if (blockIdx.x == 0) s += b3[yb] - b3[t];
    atomicAdd(&F[b * NC + t], s);
  }
}

// ---------------------------------------------------------------------------
// K5b: h[j][i1] = sum_i2 nu2[b,j,i2]*W2[i2,i1];  nu1f = h*d1.
// ---------------------------------------------------------------------------
__global__ __launch_bounds__(256) void k5b_h(
    const float* __restrict__ W2, const float* __restrict__ nu2,
    const float* __restrict__ d1B, const float* __restrict__ t1B,
    const float* __restrict__ dnB,
    float* __restrict__ nu1f, float* __restrict__ F)
{
  int b = blockIdx.y;
  int t = threadIdx.x;
  int i1 = blockIdx.x * 256 + t;
  __shared__ float nus[NC][H2];  // 40 KB
  {
    const float* src = nu2 + (size_t)b * NC * H2;
    float* dst = &nus[0][0];
    for (int idx = t; idx < NC * H2; idx += 256) dst[idx] = src[idx];
  }
  __syncthreads();
  float h[NC] = {};
  for (int i2 = 0; i2 < H2; i2 += 4) {
    float w0 = W2[(size_t)(i2 + 0) * H1 + i1];
    float w1 = W2[(size_t)(i2 + 1) * H1 + i1];
    float w2v = W2[(size_t)(i2 + 2) * H1 + i1];
    float w3 = W2[(size_t)(i2 + 3) * H1 + i1];
#pragma unroll
    for (int j = 0; j < NC; j++) {
      float4 nv = *reinterpret_cast<const float4*>(&nus[j][i2]);
      h[j] = fmaf(nv.x, w0, h[j]);
      h[j] = fmaf(nv.y, w1, h[j]);
      h[j] = fmaf(nv.z, w2v, h[j]);
      h[j] = fmaf(nv.w, w3, h[j]);
    }
  }
  float d1v = d1B[(size_t)b * H1 + i1];
  float t1v = t1B[(size_t)b * H1 + i1];
  float dnv = dnB[(size_t)b * H1 + i1];
  float sn[NC], c1[NC];
#pragma unroll
  for (int j = 0; j < NC; j++) {
    float hv = h[j];
    nu1f[((size_t)b * NC + j) * H1 + i1] = hv * d1v;
    sn[j] = hv * dnv;
    c1[j] = fmaxf(-hv, 0.f) * t1v;
  }
#pragma unroll
  for (int off = 32; off > 0; off >>= 1) {
#pragma unroll
    for (int j = 0; j < NC; j++) {
      sn[j] += __shfl_down(sn[j], off, 64);
      c1[j] += __shfl_down(c1[j], off, 64);
    }
  }
  __shared__ float red[4][2 * NC];
  int wave = t >> 6, lane = t & 63;
  if (lane == 0) {
#pragma unroll
    for (int j = 0; j < NC; j++) { red[wave][j] = sn[j]; red[wave][NC + j] = c1[j]; }
  }
  __syncthreads();
  if (t < NC) {
    float s = 0.f;
    for (int w = 0; w < 4; w++) s += red[w][t] + red[w][NC + t];
    atomicAdd(&F[b * NC + t], s);
  }
}

// ---------------------------------------------------------------------------
// K5c: Ef[b,j] = eps * sum_k |sum_i1 nu1f[b,j,i1]*W1[i1,k]|  -> F -= Ef
// ---------------------------------------------------------------------------
__global__ __launch_bounds__(256) void k5c_ef(
    const float* __restrict__ W1, const float* __restrict__ nu1f,
    float* __restrict__ F)
{
  int b = blockIdx.y;
  int t = threadIdx.x;
  int kk = blockIdx.x * 196 + t;
  bool valid = (t < 196);
  int k = valid ? kk : 0;
  __shared__ float nus[NC][H1];  // 40 KB
  {
    const float* src = nu1f + (size_t)b * NC * H1;
    float* dst = &nus[0][0];
    for (int idx = t; idx < NC * H1; idx += 256) dst[idx] = src[idx];
  }
  __syncthreads();
  float acc[NC] = {};
  for (int i1 = 0; i1 < H1; i1 += 4) {
    float a0 = W1[(size_t)(i1 + 0) * INF + k];
    float a1 = W1[(size_t)(i1 + 1) * INF + k];
    float a2 = W1[(size_t)(i1 + 2) * INF + k];
    float a3 = W1[(size_t)(i1 + 3) * INF + k];
#pragma unroll
    for (int j = 0; j < NC; j++) {
      float4 nv = *reinterpret_cast<const float4*>(&nus[j][i1]);
      acc[j] = fmaf(nv.x, a0, acc[j]);
      acc[j] = fmaf(nv.y, a1, acc[j]);
      acc[j] = fmaf(nv.z, a2, acc[j]);
      acc[j] = fmaf(nv.w, a3, acc[j]);
    }
  }
  float e[NC];
#pragma unroll
  for (int j = 0; j < NC; j++) e[j] = valid ? fabsf(acc[j]) : 0.f;
#pragma unroll
  for (int off = 32; off > 0; off >>= 1) {
#pragma unroll
    for (int j = 0; j < NC; j++) e[j] += __shfl_down(e[j], off, 64);
  }
  __shared__ float red[4][NC];
  int wave = t >> 6, lane = t & 63;
  if (lane == 0) {
#pragma unroll
    for (int j = 0; j < NC; j++) red[wave][j] = e[j];
  }
  __syncthreads();
  if (t < NC) {
    float s = 0.f;
    for (int w = 0; w < 4; w++) s += red[w][t];
    atomicAdd(&F[b * NC + t], -EPSV * s);
  }
}

// ---------------------------------------------------------------------------
// K6: out = -F
// ---------------------------------------------------------------------------
__global__ void k6_out(const float* __restrict__ F, float* __restrict__ out) {
  int t = blockIdx.x * 64 + threadIdx.x;
  if (t < B * NC) out[t] = -F[t];
}

// ---------------------------------------------------------------------------
extern "C" void kernel_launch(void* const* d_in, const int* in_sizes, int n_in,
                              void* d_out, int out_size, void* d_ws, size_t ws_size,
                              hipStream_t stream) {
  const float* x  = (const float*)d_in[0];
  const int*   y  = (const int*)  d_in[1];
  const float* W1 = (const float*)d_in[2];
  const float* b1 = (const float*)d_in[3];
  const float* W2 = (const float*)d_in[4];
  const float* b2 = (const float*)d_in[5];
  const float* W3 = (const float*)d_in[6];
  const float* b3 = (const float*)d_in[7];
  float* out = (float*)d_out;
  float* ws  = (float*)d_ws;

  float* d1B  = ws;             // 32768
  float* t1B  = ws + 32768;     // 32768
  float* dnB  = ws + 65536;     // 32768
  float* Aar  = ws + 98304;     // 32768  [j*B+b]
  float* Cl   = ws + 131072;    // 32768
  float* Cu   = ws + 163840;    // 32768
  float* E    = ws + 196608;    // 32768  [j*B+b]  (zeroed)
  float* F    = ws + 229376;    // 320 (pad to 1024, zeroed)
  float* d2B  = ws + 230400;    // 32768
  float* t2B  = ws + 263168;    // 32768
  float* db2B = ws + 295936;    // 32768
  float* nu2  = ws + 328704;    // 327680
  float* nu1f = ws + 656384;    // 327680
  ushort* W2F = (ushort*)(ws + 984064);    // 1,048,576 ushort = 2 MB (frag order)
  ushort* W1F = (ushort*)(ws + 1508352);   // 802,816 ushort = 1.57 MB (frag order)

  hipMemsetAsync(E, 0, (size_t)H2 * B * sizeof(float), stream);
  hipMemsetAsync(F, 0, (size_t)B * NC * sizeof(float), stream);

  k_pre<<<1137, 256, 0, stream>>>(x, W1, b1, W2, W1F, W2F, d1B, t1B, dnB);
  k3_mfma<<<dim3(7, 4, 32), 256, 0, stream>>>(W1F, W2F, d1B, E);
  k2_matvec<<<H2, 256, 0, stream>>>(W2, b2, dnB, t1B, Aar, Cl, Cu);
  k4_combine<<<(H2 * B + 255) / 256, 256, 0, stream>>>(Aar, Cl, Cu, E, b2, d2B, t2B, db2B);
  k5a_nu2<<<dim3(4, B), 256, 0, stream>>>(W3, b3, y, d2B, t2B, db2B, nu2, F);
  k5b_h<<<dim3(4, B), 256, 0, stream>>>(W2, nu2, d1B, t1B, dnB, nu1f, F);
  k5c_ef<<<dim3(4, B), 256, 0, stream>>>(W1, nu1f, F);
  k6_out<<<5, 64, 0, stream>>>(F, out);
}

// Round 4
// 293.115 us; speedup vs baseline: 3.5806x; 1.1314x over previous
//
#include <hip/hip_runtime.h>
#include <math.h>

#define B    32
#define INF  784
#define H1   1024
#define H2   1024
#define NC   10
#define EPSV 0.1f

typedef __attribute__((ext_vector_type(8))) short short8;
typedef __attribute__((ext_vector_type(4))) float floatx4;

__device__ inline ushort bf16_rne(float f) {
  uint u = __builtin_bit_cast(uint, f);
  u += 0x7FFFu + ((u >> 16) & 1u);
  return (ushort)(u >> 16);
}
__device__ inline uint pack2(float a, float b) {
  return (uint)bf16_rne(a) | ((uint)bf16_rne(b) << 16);
}
// scale a packed pair of bf16 (in dword u) by d0,d1 and repack
__device__ inline uint scale_pack(uint u, float d0, float d1v) {
  float f0 = __builtin_bit_cast(float, u << 16) * d0;
  float f1 = __builtin_bit_cast(float, u & 0xFFFF0000u) * d1v;
  uint r0 = __builtin_bit_cast(uint, f0) + 0x8000u;
  uint r1 = __builtin_bit_cast(uint, f1) + 0x8000u;
  return __builtin_amdgcn_perm(r1, r0, 0x07060302u);
}

// ---------------------------------------------------------------------------
// K_PRE: merged preprocessing + zero-init.
//  [0,64):     W2F fragment pack
//  [64,113):   W1F fragment pack (m-dim = k, 49 tiles, no pad)
//  [113,1137): layer-1 row i = bid-113
//  [1137,1141): zero E (4 x 8192 floats)
//  1141:       zero F
// ---------------------------------------------------------------------------
__global__ __launch_bounds__(256) void k_pre(
    const float* __restrict__ x, const float* __restrict__ W1,
    const float* __restrict__ b1, const float* __restrict__ W2,
    ushort* __restrict__ W1F, ushort* __restrict__ W2F,
    float* __restrict__ d1B, float* __restrict__ t1B, float* __restrict__ dnB,
    float* __restrict__ E, float* __restrict__ F)
{
  __shared__ float red[4][B + 1];
  int bid = blockIdx.x;
  int t = threadIdx.x;
  if (bid < 64) {
    int jt = bid;
    int lane = t & 63, c0 = t >> 6;
    int l15 = lane & 15, quad = lane >> 4;
    for (int c = c0; c < 32; c += 4) {
      const float* src = &W2[(size_t)(jt * 16 + l15) * H1 + c * 32 + quad * 8];
      float4 v0 = *reinterpret_cast<const float4*>(src);
      float4 v1 = *reinterpret_cast<const float4*>(src + 4);
      uint4 o;
      o.x = pack2(v0.x, v0.y); o.y = pack2(v0.z, v0.w);
      o.z = pack2(v1.x, v1.y); o.w = pack2(v1.z, v1.w);
      *reinterpret_cast<uint4*>(&W2F[((size_t)(c * 64 + jt) * 64 + lane) * 8]) = o;
    }
  } else if (bid < 113) {
    int mt = bid - 64;
    int lane = t & 63, c0 = t >> 6;
    int l15 = lane & 15, quad = lane >> 4;
    int col = mt * 16 + l15;
    for (int c = c0; c < 32; c += 4) {
      int r0 = c * 32 + quad * 8;
      float f[8];
#pragma unroll
      for (int e = 0; e < 8; e++) f[e] = W1[(size_t)(r0 + e) * INF + col];
      uint4 o;
      o.x = pack2(f[0], f[1]); o.y = pack2(f[2], f[3]);
      o.z = pack2(f[4], f[5]); o.w = pack2(f[6], f[7]);
      *reinterpret_cast<uint4*>(&W1F[((size_t)(c * 49 + mt) * 64 + lane) * 8]) = o;
    }
  } else if (bid < 1137) {
    int i = bid - 113;
    const float* w = W1 + (size_t)i * INF;
    float acc[B];
#pragma unroll
    for (int b = 0; b < B; b++) acc[b] = 0.f;
    float wabs = 0.f;
    for (int k = t; k < INF; k += 256) {
      float wv = w[k];
      wabs += fabsf(wv);
#pragma unroll
      for (int b = 0; b < B; b++) acc[b] = fmaf(x[b * INF + k], wv, acc[b]);
    }
#pragma unroll
    for (int off = 32; off > 0; off >>= 1) {
#pragma unroll
      for (int b = 0; b < B; b++) acc[b] += __shfl_down(acc[b], off, 64);
      wabs += __shfl_down(wabs, off, 64);
    }
    int wave = t >> 6, lane = t & 63;
    if (lane == 0) {
#pragma unroll
      for (int b = 0; b < B; b++) red[wave][b] = acc[b];
      red[wave][B] = wabs;
    }
    __syncthreads();
    if (t < B) {
      float s = red[0][t] + red[1][t] + red[2][t] + red[3][t];
      float r = EPSV * (red[0][B] + red[1][B] + red[2][B] + red[3][B]);
      float nom = s + b1[i];
      float zl = nom - r, zu = nom + r;
      float d, l;
      if (zl >= 0.f)      { d = 1.f;            l = 0.f; }
      else if (zu > 0.f)  { d = zu / (zu - zl); l = zl;  }
      else                { d = 0.f;            l = 0.f; }
      d1B[(size_t)t * H1 + i] = d;
      t1B[(size_t)t * H1 + i] = d * l;
      dnB[(size_t)t * H1 + i] = d * nom;
    }
  } else if (bid < 1141) {
    int zb = bid - 1137;
    for (int idx = t; idx < 8192; idx += 256) E[zb * 8192 + idx] = 0.f;
  } else {
    if (t < B * NC) F[t] = 0.f;
  }
}

// ---------------------------------------------------------------------------
// K3 v4: E[j,b] = eps * sum_k | sum_i W1[i,k] * (W2[j,i]*d1[b,i]) |
// Per wave: 7 m-tiles x 2 n-tiles (112k x 32j).  Block 4 waves = 64j.
// grid = (7, 8, 32b).  Register dbuf, no LDS in loop, launch_bounds(256,2).
// ---------------------------------------------------------------------------
#define K3_LOAD(c, A, Bv) do {                                                  \
  _Pragma("unroll")                                                             \
  for (int mi = 0; mi < 7; mi++)                                                \
    A[mi] = *reinterpret_cast<const uint4*>(aBase + (size_t)(c) * 25088 + mi * 512); \
  _Pragma("unroll")                                                             \
  for (int ni = 0; ni < 2; ni++)                                                \
    Bv[ni] = *reinterpret_cast<const uint4*>(bBase + (size_t)(c) * 32768 + ni * 512); \
} while (0)

#define K3_COMP(c, A, Bv) do {                                                  \
  float4 dv0 = *reinterpret_cast<const float4*>(&Ds[(c) * 32 + quad * 8]);      \
  float4 dv1 = *reinterpret_cast<const float4*>(&Ds[(c) * 32 + quad * 8 + 4]);  \
  short8 bfr[2];                                                                \
  _Pragma("unroll")                                                             \
  for (int ni = 0; ni < 2; ni++) {                                              \
    uint4 sb;                                                                   \
    sb.x = scale_pack(Bv[ni].x, dv0.x, dv0.y);                                  \
    sb.y = scale_pack(Bv[ni].y, dv0.z, dv0.w);                                  \
    sb.z = scale_pack(Bv[ni].z, dv1.x, dv1.y);                                  \
    sb.w = scale_pack(Bv[ni].w, dv1.z, dv1.w);                                  \
    bfr[ni] = __builtin_bit_cast(short8, sb);                                   \
  }                                                                             \
  _Pragma("unroll")                                                             \
  for (int mi = 0; mi < 7; mi++) {                                              \
    short8 af = __builtin_bit_cast(short8, A[mi]);                              \
    _Pragma("unroll")                                                           \
    for (int ni = 0; ni < 2; ni++)                                              \
      acc[mi][ni] = __builtin_amdgcn_mfma_f32_16x16x32_bf16(af, bfr[ni], acc[mi][ni], 0, 0, 0); \
  }                                                                             \
} while (0)

__global__ __launch_bounds__(256, 2) void k3_mfma(
    const ushort* __restrict__ W1F, const ushort* __restrict__ W2F,
    const float* __restrict__ d1B, float* __restrict__ E)
{
  int b = blockIdx.z;
  int t = threadIdx.x, w = t >> 6, lane = t & 63;
  int quad = lane >> 4, l15 = lane & 15;
  int mt0 = blockIdx.x * 7;
  int jt0 = blockIdx.y * 8 + w * 2;

  __shared__ float Ds[H1];
  for (int idx = t; idx < H1; idx += 256) Ds[idx] = d1B[(size_t)b * H1 + idx];
  __syncthreads();

  const ushort* aBase = W1F + ((size_t)mt0 * 64 + lane) * 8;  // + c*49*512
  const ushort* bBase = W2F + ((size_t)jt0 * 64 + lane) * 8;  // + c*64*512

  floatx4 acc[7][2];
#pragma unroll
  for (int mi = 0; mi < 7; mi++)
#pragma unroll
    for (int ni = 0; ni < 2; ni++) acc[mi][ni] = (floatx4){0.f, 0.f, 0.f, 0.f};

  uint4 a0[7], b0[2], a1[7], b1v[2];
  K3_LOAD(0, a0, b0);
  K3_LOAD(1, a1, b1v);
  for (int c = 0; c < 30; c += 2) {
    K3_COMP(c, a0, b0);
    K3_LOAD(c + 2, a0, b0);
    K3_COMP(c + 1, a1, b1v);
    if (c + 3 < 32) K3_LOAD(c + 3, a1, b1v);
  }
  K3_COMP(30, a0, b0);
  K3_COMP(31, a1, b1v);

#pragma unroll
  for (int ni = 0; ni < 2; ni++) {
    float s = 0.f;
#pragma unroll
    for (int mi = 0; mi < 7; mi++)
#pragma unroll
      for (int r = 0; r < 4; r++) s += fabsf(acc[mi][ni][r]);
    s += __shfl_xor(s, 16, 64);
    s += __shfl_xor(s, 32, 64);
    if (lane < 16) {
      int j = (jt0 + ni) * 16 + l15;
      atomicAdd(&E[(size_t)j * B + b], EPSV * s);
    }
  }
}

// ---------------------------------------------------------------------------
// K2: A / crossl / crossu matvecs.  One block per j (row of W2).
// ---------------------------------------------------------------------------
__global__ __launch_bounds__(256) void k2_matvec(
    const float* __restrict__ W2, const float* __restrict__ b2,
    const float* __restrict__ dnB, const float* __restrict__ t1B,
    float* __restrict__ A, float* __restrict__ Cl, float* __restrict__ Cu)
{
  int j = blockIdx.x;
  int t = threadIdx.x;
  int wave = t >> 6, lane = t & 63;
  int b0 = wave * 8;
  float aA[8] = {}, aCl[8] = {}, aCu[8] = {};
  const float* __restrict__ w2 = W2 + (size_t)j * H1;
  for (int i = lane; i < H1; i += 64) {
    float wv = w2[i];
    float wp = fmaxf(wv, 0.f), wn = fmaxf(-wv, 0.f);
#pragma unroll
    for (int r = 0; r < 8; r++) {
      float dv = dnB[(size_t)(b0 + r) * H1 + i];
      float tv = t1B[(size_t)(b0 + r) * H1 + i];
      aA[r]  = fmaf(wv, dv, aA[r]);
      aCl[r] = fmaf(wn, tv, aCl[r]);
      aCu[r] = fmaf(wp, tv, aCu[r]);
    }
  }
#pragma unroll
  for (int off = 32; off > 0; off >>= 1) {
#pragma unroll
    for (int r = 0; r < 8; r++) {
      aA[r]  += __shfl_down(aA[r],  off, 64);
      aCl[r] += __shfl_down(aCl[r], off, 64);
      aCu[r] += __shfl_down(aCu[r], off, 64);
    }
  }
  if (lane == 0) {
    float bj = b2[j];
#pragma unroll
    for (int r = 0; r < 8; r++) {
      A [(size_t)j * B + b0 + r] = aA[r] + bj;
      Cl[(size_t)j * B + b0 + r] = aCl[r];
      Cu[(size_t)j * B + b0 + r] = aCu[r];
    }
  }
}

// ---------------------------------------------------------------------------
// K4: combine -> d2, t2, db2 (b-major [b][H2])
// ---------------------------------------------------------------------------
__global__ __launch_bounds__(256) void k4_combine(
    const float* __restrict__ A, const float* __restrict__ Cl,
    const float* __restrict__ Cu, const float* __restrict__ E,
    const float* __restrict__ b2,
    float* __restrict__ d2B, float* __restrict__ t2B, float* __restrict__ db2B)
{
  int idx = blockIdx.x * 256 + threadIdx.x;  // idx = j*B + b
  if (idx >= H2 * B) return;
  int j = idx >> 5, b = idx & 31;
  float a = A[idx], e = E[idx];
  float zl = a - e + Cl[idx];
  float zu = a + e - Cu[idx];
  float d, l;
  if (zl >= 0.f)      { d = 1.f;            l = 0.f; }
  else if (zu > 0.f)  { d = zu / (zu - zl); l = zl;  }
  else                { d = 0.f;            l = 0.f; }
  d2B [(size_t)b * H2 + j] = d;
  t2B [(size_t)b * H2 + j] = d * l;
  db2B[(size_t)b * H2 + j] = d * b2[j];
}

// ---------------------------------------------------------------------------
// K5a: nu2T[b][i2][j] (stride 12) = (W3[y_b,i2]-W3[j,i2])*d2[b,i2]
// grid (4 i-slices, 32 b).  Also F += c.b3 + nu2.db2 + relu(-nu2).t2m parts.
// ---------------------------------------------------------------------------
__global__ __launch_bounds__(256) void k5a_nu2(
    const float* __restrict__ W3, const float* __restrict__ b3,
    const int* __restrict__ y,
    const float* __restrict__ d2B, const float* __restrict__ t2B,
    const float* __restrict__ db2B,
    float* __restrict__ nu2T, float* __restrict__ F)
{
  int b = blockIdx.y;
  int t = threadIdx.x;
  int i = blockIdx.x * 256 + t;
  int yb = y[b];
  float d2v = d2B[(size_t)b * H2 + i];
  float t2v = t2B[(size_t)b * H2 + i];
  float dbv = db2B[(size_t)b * H2 + i];
  float wy = W3[(size_t)yb * H2 + i];
  float accB[NC], accC[NC];
#pragma unroll
  for (int j = 0; j < NC; j++) {
    float cw = wy - W3[(size_t)j * H2 + i];
    nu2T[((size_t)b * H2 + i) * 12 + j] = cw * d2v;
    accB[j] = cw * dbv;
    accC[j] = fmaxf(-cw, 0.f) * t2v;
  }
#pragma unroll
  for (int off = 32; off > 0; off >>= 1) {
#pragma unroll
    for (int j = 0; j < NC; j++) {
      accB[j] += __shfl_down(accB[j], off, 64);
      accC[j] += __shfl_down(accC[j], off, 64);
    }
  }
  __shared__ float red[4][2 * NC];
  int wave = t >> 6, lane = t & 63;
  if (lane == 0) {
#pragma unroll
    for (int j = 0; j < NC; j++) { red[wave][j] = accB[j]; red[wave][NC + j] = accC[j]; }
  }
  __syncthreads();
  if (t < NC) {
    float s = 0.f;
    for (int w = 0; w < 4; w++) s += red[w][t] + red[w][NC + t];
    if (blockIdx.x == 0) s += b3[yb] - b3[t];
    atomicAdd(&F[b * NC + t], s);
  }
}

// ---------------------------------------------------------------------------
// K5b1: hpart[s][b][j][i1] = sum_{i2 in half s} nu2T[b][i2][j] * W2[i2,i1]
// nu2T reads are wave-uniform -> scalar loads (SGPR operand FMAs).
// grid (8 i1-tiles of 128, 32 b, 2 s), block 128.
// ---------------------------------------------------------------------------
__global__ __launch_bounds__(128) void k5b1(
    const float* __restrict__ W2, const float* __restrict__ nu2T,
    float* __restrict__ hpart)
{
  int t = threadIdx.x;
  int i1 = blockIdx.x * 128 + t;
  int b = blockIdx.y, s = blockIdx.z;
  const float* __restrict__ nrowb = nu2T + ((size_t)b * H2 + s * 512) * 12;
  const float* __restrict__ w2b = W2 + (size_t)s * 512 * H1 + i1;
  float h[NC] = {};
  for (int i2 = 0; i2 < 512; i2++) {
    float w2v = w2b[(size_t)i2 * H1];
    const float* __restrict__ nrow = nrowb + i2 * 12;
#pragma unroll
    for (int j = 0; j < NC; j++) h[j] = fmaf(nrow[j], w2v, h[j]);
  }
#pragma unroll
  for (int j = 0; j < NC; j++)
    hpart[(((size_t)s * B + b) * NC + j) * H1 + i1] = h[j];
}

// ---------------------------------------------------------------------------
// K5b2: h = hpart0+hpart1; nu1fT[b][i1][j] = h*d1; F += h*dn + relu(-h)*t1m
// grid (4, 32), block 256.
// ---------------------------------------------------------------------------
__global__ __launch_bounds__(256) void k5b2(
    const float* __restrict__ hpart,
    const float* __restrict__ d1B, const float* __restrict__ t1B,
    const float* __restrict__ dnB,
    float* __restrict__ nu1fT, float* __restrict__ F)
{
  int t = threadIdx.x;
  int i1 = blockIdx.x * 256 + t;
  int b = blockIdx.y;
  float d1v = d1B[(size_t)b * H1 + i1];
  float t1v = t1B[(size_t)b * H1 + i1];
  float dnv = dnB[(size_t)b * H1 + i1];
  float sn[NC], c1[NC];
#pragma unroll
  for (int j = 0; j < NC; j++) {
    float hv = hpart[((size_t)b * NC + j) * H1 + i1]
             + hpart[(((size_t)B + b) * NC + j) * H1 + i1];
    nu1fT[((size_t)b * H1 + i1) * 12 + j] = hv * d1v;
    sn[j] = hv * dnv;
    c1[j] = fmaxf(-hv, 0.f) * t1v;
  }
#pragma unroll
  for (int off = 32; off > 0; off >>= 1) {
#pragma unroll
    for (int j = 0; j < NC; j++) {
      sn[j] += __shfl_down(sn[j], off, 64);
      c1[j] += __shfl_down(c1[j], off, 64);
    }
  }
  __shared__ float red[4][2 * NC];
  int wave = t >> 6, lane = t & 63;
  if (lane == 0) {
#pragma unroll
    for (int j = 0; j < NC; j++) { red[wave][j] = sn[j]; red[wave][NC + j] = c1[j]; }
  }
  __syncthreads();
  if (t < NC) {
    float s = 0.f;
    for (int w = 0; w < 4; w++) s += red[w][t] + red[w][NC + t];
    atomicAdd(&F[b * NC + t], s);
  }
}

// ---------------------------------------------------------------------------
// K5c1: ppart[s][b][j][k] = sum_{i1 in half s} nu1fT[b][i1][j] * W1[i1,k]
// grid (7 k-tiles of 112, 32 b, 2 s), block 128 (t<112 active).
// ---------------------------------------------------------------------------
__global__ __launch_bounds__(128) void k5c1(
    const float* __restrict__ W1, const float* __restrict__ nu1fT,
    float* __restrict__ ppart)
{
  int t = threadIdx.x;
  bool valid = (t < 112);
  int k = blockIdx.x * 112 + (valid ? t : 0);
  int b = blockIdx.y, s = blockIdx.z;
  const float* __restrict__ nrowb = nu1fT + ((size_t)b * H1 + s * 512) * 12;
  const float* __restrict__ w1b = W1 + (size_t)s * 512 * INF + k;
  float acc[NC] = {};
  for (int i1 = 0; i1 < 512; i1++) {
    float w1v = w1b[(size_t)i1 * INF];
    const float* __restrict__ nrow = nrowb + i1 * 12;
#pragma unroll
    for (int j = 0; j < NC; j++) acc[j] = fmaf(nrow[j], w1v, acc[j]);
  }
  if (valid) {
#pragma unroll
    for (int j = 0; j < NC; j++)
      ppart[(((size_t)s * B + b) * NC + j) * INF + k] = acc[j];
  }
}

// ---------------------------------------------------------------------------
// K5c2 + out: per b: Ef[j] = eps*sum_k |p0+p1|; out = eps*Ef - F.
// grid (32), block 256.
// ---------------------------------------------------------------------------
__global__ __launch_bounds__(256) void k5c2_out(
    const float* __restrict__ ppart, const float* __restrict__ F,
    float* __restrict__ out)
{
  int b = blockIdx.x;
  int t = threadIdx.x;
  float e[NC] = {};
  for (int k = t; k < INF; k += 256) {
#pragma unroll
    for (int j = 0; j < NC; j++) {
      float v = ppart[((size_t)b * NC + j) * INF + k]
              + ppart[(((size_t)B + b) * NC + j) * INF + k];
      e[j] += fabsf(v);
    }
  }
#pragma unroll
  for (int off = 32; off > 0; off >>= 1) {
#pragma unroll
    for (int j = 0; j < NC; j++) e[j] += __shfl_down(e[j], off, 64);
  }
  __shared__ float red[4][NC];
  int wave = t >> 6, lane = t & 63;
  if (lane == 0) {
#pragma unroll
    for (int j = 0; j < NC; j++) red[wave][j] = e[j];
  }
  __syncthreads();
  if (t < NC) {
    float s = 0.f;
    for (int w = 0; w < 4; w++) s += red[w][t];
    out[b * NC + t] = EPSV * s - F[b * NC + t];
  }
}

// ---------------------------------------------------------------------------
extern "C" void kernel_launch(void* const* d_in, const int* in_sizes, int n_in,
                              void* d_out, int out_size, void* d_ws, size_t ws_size,
                              hipStream_t stream) {
  const float* x  = (const float*)d_in[0];
  const int*   y  = (const int*)  d_in[1];
  const float* W1 = (const float*)d_in[2];
  const float* b1 = (const float*)d_in[3];
  const float* W2 = (const float*)d_in[4];
  const float* b2 = (const float*)d_in[5];
  const float* W3 = (const float*)d_in[6];
  const float* b3 = (const float*)d_in[7];
  float* out = (float*)d_out;
  float* ws  = (float*)d_ws;

  // ---- workspace layout (floats), with lifetime overlays ----
  float* d1B  = ws;             //   0..32768
  float* t1B  = ws + 32768;
  float* dnB  = ws + 65536;
  float* Aar  = ws + 98304;     // k2 -> k4
  float* Cl   = ws + 131072;
  float* Cu   = ws + 163840;
  float* E    = ws + 196608;    // zeroed in k_pre, k3 -> k4
  float* F    = ws + 229376;    // 320 used (zeroed in k_pre)
  float* d2B  = ws + 230400;    // k4 -> k5a
  float* t2B  = ws + 263168;
  float* db2B = ws + 295936;
  float* nu2T = ws + 328704;    // 393216 floats, k5a -> k5b1 (ends 721920)
  ushort* W2F = (ushort*)(ws + 721920);    // 1048576 us = 524288 f (ends 1246208)
  ushort* W1F = (ushort*)(ws + 1246208);   // 802816 us = 401408 f (ends 1647616)
  // overlays (disjoint lifetimes):
  float* nu1fT = ws + 230400;   // 393216 floats over d2B/t2B/db2B/nu2T (k5b2 -> k5c1)
  float* hpart = ws + 721920;   // 655360 floats over W2F/W1F (k5b1 -> k5b2)
  float* ppart = ws + 721920;   // 501760 floats, same region (k5c1 -> k5c2)

  k_pre<<<1142, 256, 0, stream>>>(x, W1, b1, W2, W1F, W2F, d1B, t1B, dnB, E, F);
  k3_mfma<<<dim3(7, 8, 32), 256, 0, stream>>>(W1F, W2F, d1B, E);
  k2_matvec<<<H2, 256, 0, stream>>>(W2, b2, dnB, t1B, Aar, Cl, Cu);
  k4_combine<<<(H2 * B + 255) / 256, 256, 0, stream>>>(Aar, Cl, Cu, E, b2, d2B, t2B, db2B);
  k5a_nu2<<<dim3(4, B), 256, 0, stream>>>(W3, b3, y, d2B, t2B, db2B, nu2T, F);
  k5b1<<<dim3(8, B, 2), 128, 0, stream>>>(W2, nu2T, hpart);
  k5b2<<<dim3(4, B), 256, 0, stream>>>(hpart, d1B, t1B, dnB, nu1fT, F);
  k5c1<<<dim3(7, B, 2), 128, 0, stream>>>(W1, nu1fT, ppart);
  k5c2_out<<<B, 256, 0, stream>>>(ppart, F, out);
}